// Round 3
// baseline (94.783 us; speedup 1.0000x reference)
//
#include <hip/hip_runtime.h>
#include <math.h>

#define N_ 6
#define C_ 256
#define H_ 180
#define W_ 320
#define HW_ (H_*W_)
#define P_ 25600        // 40*40*16
#define P4_ (P_/4)      // 6400
#define DH_ 360
#define DW_ 640
#define CG_ 8           // channels per thread

typedef float floatx4 __attribute__((ext_vector_type(4)));

// jax.image.resize linear+antialias, scale=1/2: output i samples input coord 2i+0.5,
// triangle kernel scaled by 2 -> taps {2i-1..2i+2}, raw weights {.25,.75,.75,.25},
// renormalized after dropping out-of-range taps (edges: /1.75 instead of /2).
__device__ __forceinline__ void resize_taps(int i, int m_in, int idx[4], float w[4]) {
    const float kv0 = 0.25f, kv1 = 0.75f;
    int j0 = 2*i - 1;
    float s = 0.f;
    #pragma unroll
    for (int t = 0; t < 4; ++t) {
        int j = j0 + t;
        bool ok = (j >= 0) && (j < m_in);
        idx[t] = ok ? j : 0;
        float kv = (t == 0 || t == 3) ? kv0 : kv1;
        w[t] = ok ? kv : 0.f;
        s = __fadd_rn(s, w[t]);
    }
    #pragma unroll
    for (int t = 0; t < 4; ++t) w[t] = __fdiv_rn(w[t], s);
}

__global__ void prep_kernel(const float* __restrict__ points,
                            const float* __restrict__ proj,
                            const float* __restrict__ depth,
                            const float* __restrict__ offsets,
                            float* __restrict__ valid_out,
                            float* __restrict__ pts3d_out,
                            int*   __restrict__ linflag) {
    int idx = blockIdx.x * blockDim.x + threadIdx.x;
    if (idx >= N_*P_) return;
    int n = idx / P_;
    int p = idx - n*P_;

    float X = points[p];
    float Y = points[P_ + p];
    float Z = points[2*P_ + p];

    const float* K = proj + n*12;
    // einsum dot, sequential f32, no fma contraction
    float p0 = __fadd_rn(__fadd_rn(__fadd_rn(__fmul_rn(K[0],X), __fmul_rn(K[1],Y)), __fmul_rn(K[2],Z)), K[3]);
    float p1 = __fadd_rn(__fadd_rn(__fadd_rn(__fmul_rn(K[4],X), __fmul_rn(K[5],Y)), __fmul_rn(K[6],Z)), K[7]);
    float z  = __fadd_rn(__fadd_rn(__fadd_rn(__fmul_rn(K[8],X), __fmul_rn(K[9],Y)), __fmul_rn(K[10],Z)), K[11]);

    float o0 = __fmul_rn(tanhf(offsets[2*p]),     5.0f);
    float o1 = __fmul_rn(tanhf(offsets[2*p + 1]), 5.0f);

    float x = __fadd_rn(__fdiv_rn(p0, z), o0);
    float y = __fadd_rn(__fdiv_rn(p1, z), o1);

    int xi = (int)rintf(x);   // rintf = round half to even = jnp.round
    int yi = (int)rintf(y);

    bool valid = (xi >= 0) && (yi >= 0) && (xi < W_) && (yi < H_) && (z > 0.f);

    int xc = min(max(xi, 0), W_-1);
    int yc = min(max(yi, 0), H_-1);

    int ri[4], ci[4];
    float rw[4], cw[4];
    resize_taps(yc, DH_, ri, rw);
    resize_taps(xc, DW_, ci, cw);

    const float* dbase = depth + (size_t)n * (DH_*DW_);
    // H-contraction first, then W, each sequential f32 (matches weight-matrix einsum)
    float dg = 0.f;
    #pragma unroll
    for (int t = 0; t < 4; ++t) {
        int c = ci[t];
        float acc = 0.f;
        #pragma unroll
        for (int u = 0; u < 4; ++u) {
            acc = __fadd_rn(acc, __fmul_rn(rw[u], dbase[ri[u]*DW_ + c]));
        }
        dg = __fadd_rn(dg, __fmul_rn(cw[t], acc));
    }

    valid = valid && (z > __fsub_rn(dg, 0.5f)) && (z < __fadd_rn(dg, 0.5f));

    int lin = yc*W_ + xc;
    float vm = valid ? 1.0f : 0.0f;

    valid_out[idx] = vm;
    float* p3 = pts3d_out + (size_t)n * (3*P_);
    p3[p]        = X * vm;
    p3[P_ + p]   = Y * vm;
    p3[2*P_ + p] = Z * vm;
    linflag[idx] = valid ? lin : -1;
}

// Each thread: one (n, p4) group of 4 points x CG_ channels.
// One linflag int4 read amortized over CG_ channels; 4*CG_ scattered
// predicated loads in flight; nontemporal float4 stores (volume stream
// is write-once -> keep L2 for feature-line reuse).
__global__ void __launch_bounds__(256)
fill_kernel(const float* __restrict__ feat,
            const int*   __restrict__ linflag,
            float* __restrict__ vol) {
    int tid = blockIdx.x * 256 + threadIdx.x;      // over N_*(C_/CG_)*P4_, exact
    int p4   = tid % P4_;
    int rest = tid / P4_;                          // (cg, n): n fastest
    int n  = rest % N_;
    int cg = rest / N_;

    const int4 lf = *reinterpret_cast<const int4*>(linflag + n*P_ + p4*4);

    const float* fb = feat + ((size_t)(n*C_ + cg*CG_)) * HW_;
    float* vb = vol + ((size_t)(n*C_ + cg*CG_)) * P_ + p4*4;

    #pragma unroll
    for (int i = 0; i < CG_; ++i) {
        floatx4 v;
        v.x = (lf.x >= 0) ? fb[lf.x] : 0.f;
        v.y = (lf.y >= 0) ? fb[lf.y] : 0.f;
        v.z = (lf.z >= 0) ? fb[lf.z] : 0.f;
        v.w = (lf.w >= 0) ? fb[lf.w] : 0.f;
        __builtin_nontemporal_store(v, reinterpret_cast<floatx4*>(vb));
        fb += HW_;
        vb += P_;
    }
}

extern "C" void kernel_launch(void* const* d_in, const int* in_sizes, int n_in,
                              void* d_out, int out_size, void* d_ws, size_t ws_size,
                              hipStream_t stream) {
    const float* features = (const float*)d_in[0];   // (6,256,180,320)
    const float* points   = (const float*)d_in[1];   // (3,40,40,16)
    const float* proj     = (const float*)d_in[2];   // (6,3,4)
    const float* depth    = (const float*)d_in[3];   // (6,360,640)
    const float* offsets  = (const float*)d_in[4];   // (1,25600,2)

    float* out = (float*)d_out;
    float* vol       = out;                                  // 6*256*25600
    float* valid_out = out + (size_t)N_*C_*P_;               // 6*25600
    float* pts3d_out = valid_out + (size_t)N_*P_;            // 6*3*25600

    int* linflag = (int*)d_ws;                               // 6*25600 ints

    {
        int total = N_*P_;
        int blocks = (total + 255) / 256;
        prep_kernel<<<blocks, 256, 0, stream>>>(points, proj, depth, offsets,
                                                valid_out, pts3d_out, linflag);
    }
    {
        int total = N_*(C_/CG_)*P4_;     // 1,228,800 — divisible by 256
        int blocks = total / 256;
        fill_kernel<<<blocks, 256, 0, stream>>>(features, linflag, vol);
    }
}

// Round 4
// 87.969 us; speedup vs baseline: 1.0775x; 1.0775x over previous
//
#include <hip/hip_runtime.h>
#include <math.h>

#define N_ 6
#define C_ 256
#define H_ 180
#define W_ 320
#define HW_ (H_*W_)
#define P_ 25600        // 40*40*16, p = (ix*40+iy)*16+iz
#define DH_ 360
#define DW_ 640

typedef float floatx4 __attribute__((ext_vector_type(4)));

// jax.image.resize linear+antialias, scale=1/2: output i samples input coord 2i+0.5,
// triangle kernel scaled by 2 -> taps {2i-1..2i+2}, raw weights {.25,.75,.75,.25},
// renormalized after dropping out-of-range taps (edges: /1.75 instead of /2).
__device__ __forceinline__ void resize_taps(int i, int m_in, int idx[4], float w[4]) {
    const float kv0 = 0.25f, kv1 = 0.75f;
    int j0 = 2*i - 1;
    float s = 0.f;
    #pragma unroll
    for (int t = 0; t < 4; ++t) {
        int j = j0 + t;
        bool ok = (j >= 0) && (j < m_in);
        idx[t] = ok ? j : 0;
        float kv = (t == 0 || t == 3) ? kv0 : kv1;
        w[t] = ok ? kv : 0.f;
        s = __fadd_rn(s, w[t]);
    }
    #pragma unroll
    for (int t = 0; t < 4; ++t) w[t] = __fdiv_rn(w[t], s);
}

__global__ void prep_kernel(const float* __restrict__ points,
                            const float* __restrict__ proj,
                            const float* __restrict__ depth,
                            const float* __restrict__ offsets,
                            float* __restrict__ valid_out,
                            float* __restrict__ pts3d_out,
                            int*   __restrict__ linflagT) {
    int idx = blockIdx.x * blockDim.x + threadIdx.x;
    if (idx >= N_*P_) return;
    int n = idx / P_;
    int p = idx - n*P_;

    float X = points[p];
    float Y = points[P_ + p];
    float Z = points[2*P_ + p];

    const float* K = proj + n*12;
    // einsum dot, sequential f32, no fma contraction
    float p0 = __fadd_rn(__fadd_rn(__fadd_rn(__fmul_rn(K[0],X), __fmul_rn(K[1],Y)), __fmul_rn(K[2],Z)), K[3]);
    float p1 = __fadd_rn(__fadd_rn(__fadd_rn(__fmul_rn(K[4],X), __fmul_rn(K[5],Y)), __fmul_rn(K[6],Z)), K[7]);
    float z  = __fadd_rn(__fadd_rn(__fadd_rn(__fmul_rn(K[8],X), __fmul_rn(K[9],Y)), __fmul_rn(K[10],Z)), K[11]);

    float o0 = __fmul_rn(tanhf(offsets[2*p]),     5.0f);
    float o1 = __fmul_rn(tanhf(offsets[2*p + 1]), 5.0f);

    float x = __fadd_rn(__fdiv_rn(p0, z), o0);
    float y = __fadd_rn(__fdiv_rn(p1, z), o1);

    int xi = (int)rintf(x);   // rintf = round half to even = jnp.round
    int yi = (int)rintf(y);

    bool valid = (xi >= 0) && (yi >= 0) && (xi < W_) && (yi < H_) && (z > 0.f);

    int xc = min(max(xi, 0), W_-1);
    int yc = min(max(yi, 0), H_-1);

    int ri[4], ci[4];
    float rw[4], cw[4];
    resize_taps(yc, DH_, ri, rw);
    resize_taps(xc, DW_, ci, cw);

    const float* dbase = depth + (size_t)n * (DH_*DW_);
    // H-contraction first, then W, each sequential f32 (matches weight-matrix einsum)
    float dg = 0.f;
    #pragma unroll
    for (int t = 0; t < 4; ++t) {
        int c = ci[t];
        float acc = 0.f;
        #pragma unroll
        for (int u = 0; u < 4; ++u) {
            acc = __fadd_rn(acc, __fmul_rn(rw[u], dbase[ri[u]*DW_ + c]));
        }
        dg = __fadd_rn(dg, __fmul_rn(cw[t], acc));
    }

    valid = valid && (z > __fsub_rn(dg, 0.5f)) && (z < __fadd_rn(dg, 0.5f));

    int lin = yc*W_ + xc;
    float vm = valid ? 1.0f : 0.0f;

    valid_out[idx] = vm;
    float* p3 = pts3d_out + (size_t)n * (3*P_);
    p3[p]        = X * vm;
    p3[P_ + p]   = Y * vm;
    p3[2*P_ + p] = Z * vm;

    // transposed: [iy][iz][ix], ix fastest -> ix-contiguous int4 reads in fill
    int ix = p / 640;
    int rem = p - ix*640;
    int iy = rem / 16;
    int iz = rem - iy*16;
    linflagT[n*P_ + iy*640 + iz*40 + ix] = valid ? lin : -1;
}

// Block (320 thr) = 2 channels x one (n, iy) slab of 40x16 points.
// Gather phase: thread r -> (iz = r/10, ix4 = r%10): int4 of 4 consecutive ix,
//   gathers land on 1-2 shared feature lines (x-adjacent pixels), same-row lanes
//   coalesce in the TA. Results staged in LDS.
// Store phase (after transpose): thread r -> (col = r/4, z4 = r%4): one float4 of
//   consecutive z -> 4 lanes fully cover one 64B volume line; nontemporal so the
//   157MB store stream doesn't evict feature lines from L2.
__global__ void __launch_bounds__(320)
fill_kernel(const float* __restrict__ feat,
            const int*   __restrict__ linflagT,
            float* __restrict__ vol) {
    __shared__ float smem[2][16][41];   // +1 pad vs bank conflicts

    int b  = blockIdx.x;                // (n, iy, cp), cp fastest
    int cp = b % (C_/2);
    int t  = b / (C_/2);
    int iy = t % 40;
    int n  = t / 40;

    int tid = threadIdx.x;              // 0..319
    int ch  = tid / 160;                // 0,1
    int r   = tid - ch*160;             // 0..159
    int c   = cp*2 + ch;

    // ---- gather ----
    int iz  = r / 10;
    int ix4 = r - iz*10;
    const int4 lf = *reinterpret_cast<const int4*>(linflagT + n*P_ + iy*640 + iz*40 + ix4*4);
    const float* fb = feat + (size_t)(n*C_ + c) * HW_;
    smem[ch][iz][ix4*4+0] = (lf.x >= 0) ? fb[lf.x] : 0.f;
    smem[ch][iz][ix4*4+1] = (lf.y >= 0) ? fb[lf.y] : 0.f;
    smem[ch][iz][ix4*4+2] = (lf.z >= 0) ? fb[lf.z] : 0.f;
    smem[ch][iz][ix4*4+3] = (lf.w >= 0) ? fb[lf.w] : 0.f;

    __syncthreads();

    // ---- transpose + store ----
    int col = r / 4;                    // ix 0..39
    int z4  = r - col*4;                // 0..3
    floatx4 v;
    v.x = smem[ch][z4*4+0][col];
    v.y = smem[ch][z4*4+1][col];
    v.z = smem[ch][z4*4+2][col];
    v.w = smem[ch][z4*4+3][col];
    float* dst = vol + (size_t)(n*C_ + c) * P_ + (col*40 + iy)*16 + z4*4;
    __builtin_nontemporal_store(v, reinterpret_cast<floatx4*>(dst));
}

extern "C" void kernel_launch(void* const* d_in, const int* in_sizes, int n_in,
                              void* d_out, int out_size, void* d_ws, size_t ws_size,
                              hipStream_t stream) {
    const float* features = (const float*)d_in[0];   // (6,256,180,320)
    const float* points   = (const float*)d_in[1];   // (3,40,40,16)
    const float* proj     = (const float*)d_in[2];   // (6,3,4)
    const float* depth    = (const float*)d_in[3];   // (6,360,640)
    const float* offsets  = (const float*)d_in[4];   // (1,25600,2)

    float* out = (float*)d_out;
    float* vol       = out;                                  // 6*256*25600
    float* valid_out = out + (size_t)N_*C_*P_;               // 6*25600
    float* pts3d_out = valid_out + (size_t)N_*P_;            // 6*3*25600

    int* linflagT = (int*)d_ws;                              // 6*25600 ints

    {
        int total = N_*P_;
        int blocks = (total + 255) / 256;
        prep_kernel<<<blocks, 256, 0, stream>>>(points, proj, depth, offsets,
                                                valid_out, pts3d_out, linflagT);
    }
    {
        int blocks = N_ * 40 * (C_/2);   // 30,720
        fill_kernel<<<blocks, 320, 0, stream>>>(features, linflagT, vol);
    }
}